// Round 21
// baseline (126.041 us; speedup 1.0000x reference)
//
#include <hip/hip_runtime.h>
#include <hip/hip_bf16.h>
#include <math.h>

typedef __bf16 bf16;
typedef __bf16 bf16x8 __attribute__((ext_vector_type(8)));
typedef float f32x4 __attribute__((ext_vector_type(4)));
typedef unsigned int u32x2 __attribute__((ext_vector_type(2)));

constexpr int B = 4, S = 2048, E = 1024, H = 16, HD = 64;

// 0.125 (1/sqrt(64)) * log2(e): scores in log2 domain -> raw v_exp_f32
constexpr float QSCALE = 0.125f * 1.44269504088896340736f;
// defer-max threshold (T13): 8 nats in log2 domain
constexpr float DTHR = 11.5f;

static __device__ __forceinline__ float exp2_fast(float x) {
#if __has_builtin(__builtin_amdgcn_exp2f)
    return __builtin_amdgcn_exp2f(x);
#else
    float r; asm("v_exp_f32 %0, %1" : "=v"(r) : "v"(x)); return r;
#endif
}

static __device__ __forceinline__ unsigned pk_bf16(float a, float b) {
    union { bf16 h[2]; unsigned u; } r;
    r.h[0] = (bf16)a; r.h[1] = (bf16)b;
    return r.u;
}

// 3-input max (clang fuses nested fmaxf to v_max3_f32 — T17)
static __device__ __forceinline__ float max3(float a, float b, float c) {
    return fmaxf(fmaxf(a, b), c);
}

// async global->LDS DMA, 16B/lane (block-wide staging only — measured win in
// out_gemm/qkv W-tile; measured regression in attn's wave-sliced staging).
static __device__ __forceinline__ void gl16(const void* g, void* l) {
    __builtin_amdgcn_global_load_lds(
        (__attribute__((address_space(1))) void*)g,
        (__attribute__((address_space(3))) void*)l,
        16, 0, 0);
}

// ---------------------------------------------------------------------------
// Kernel 0: fused weight prep.
// ---------------------------------------------------------------------------
__global__ __launch_bounds__(256) void prep_weights(
    const float* __restrict__ Wq, const float* __restrict__ Wk,
    const float* __restrict__ Wv, const float* __restrict__ Wp,
    bf16* __restrict__ Wt, bf16* __restrict__ Wpt)
{
    __shared__ float t[64][65];
    const int tid = threadIdx.x;
    const int x = blockIdx.x, y = blockIdx.y;
    if (y < 3) {
        const int h = x, p = y;
        const float* W = (p == 0) ? Wq : (p == 1) ? Wk : Wv;
        const float scale = (p == 0) ? QSCALE : 1.0f;
        #pragma unroll
        for (int i = 0; i < 16; ++i) {
            int idx = tid + i * 256;
            int d = idx >> 6, e = idx & 63;
            t[d][e] = W[(size_t)h * 4096 + d * 64 + e];
        }
        __syncthreads();
        bf16* dst = Wt + ((size_t)p * H + h) * 4096;
        #pragma unroll
        for (int i = 0; i < 16; ++i) {
            int idx = tid + i * 256;
            int e = idx >> 6, d = idx & 63;
            dst[e * 64 + d] = (bf16)(t[d][e] * scale);
        }
    } else {
        const int k0 = (y - 3) * 64, n0 = x * 64;
        #pragma unroll
        for (int i = 0; i < 16; ++i) {
            int idx = tid + i * 256;
            int r = idx >> 6, c = idx & 63;
            t[r][c] = Wp[(size_t)(k0 + r) * E + n0 + c];
        }
        __syncthreads();
        #pragma unroll
        for (int i = 0; i < 16; ++i) {
            int idx = tid + i * 256;
            int r = idx >> 6, c = idx & 63;
            Wpt[(size_t)(n0 + r) * E + k0 + c] = (bf16)t[c][r];
        }
    }
}

// ---------------------------------------------------------------------------
// Kernel 1: QKV projections via MFMA (verified 16x16x32 contract).
// W tile staged via gl16 (block-wide bf16, pre-swizzled src — measured R14).
// ---------------------------------------------------------------------------
__global__ __launch_bounds__(256) void qkv_proj(
    const float* __restrict__ xq, const float* __restrict__ xk, const float* __restrict__ xv,
    const bf16* __restrict__ Wt,
    const float* __restrict__ bq, const float* __restrict__ bk, const float* __restrict__ bv,
    bf16* __restrict__ Qb, bf16* __restrict__ Kb, bf16* __restrict__ Vt)
{
    const int b = blockIdx.z, h = blockIdx.y, s0 = blockIdx.x * 128;
    const int tid = threadIdx.x;
    const int w = tid >> 6, l = tid & 63;
    const int l16 = l & 15, lg = l >> 4;
    const size_t bh = (size_t)b * H + h;

    __shared__ __align__(16) bf16 xs[128][64];
    __shared__ __align__(16) bf16 Wl[64][64];
    __shared__ __align__(16) bf16 ts[10240];

    const int r8 = l >> 3;
    const int wchunk = ((l & 7) ^ r8) * 8;   // lane-constant swizzled chunk

    for (int p = 0; p < 3; ++p) {
        const float* x    = (p == 0) ? xq : (p == 1) ? xk : xv;
        const float* bias = (p == 0) ? bq : (p == 1) ? bk : bv;
        const float  bsc  = (p == 0) ? QSCALE : 1.0f;

        __syncthreads();
        // ---- W^T [64][64] bf16 via gl16 (2 issues/thread) ----
        const bf16* wsrc = Wt + ((size_t)p * H + h) * 4096;
        #pragma unroll
        for (int i = 0; i < 2; ++i) {
            const int rb = 8 * (w + 4 * i);
            gl16(wsrc + (size_t)(rb + r8) * 64 + wchunk, &Wl[rb][0]);
        }
        // ---- stage x tile [128][64] fp32 -> bf16 swizzled (reg path) ----
        #pragma unroll
        for (int i = 0; i < 4; ++i) {
            int idx = tid + i * 256;
            int r = idx >> 3, g = idx & 7;
            const float* src = &x[((size_t)b * S + s0 + r) * E + h * 64 + g * 8];
            float4 f0 = *(const float4*)src;
            float4 f1 = *(const float4*)(src + 4);
            union { bf16 h8[8]; uint4 u; } pk;
            pk.h8[0] = (bf16)f0.x; pk.h8[1] = (bf16)f0.y;
            pk.h8[2] = (bf16)f0.z; pk.h8[3] = (bf16)f0.w;
            pk.h8[4] = (bf16)f1.x; pk.h8[5] = (bf16)f1.y;
            pk.h8[6] = (bf16)f1.z; pk.h8[7] = (bf16)f1.w;
            *(uint4*)&xs[r][(g ^ (r & 7)) * 8] = pk.u;
        }
        __syncthreads();

        if (p < 2) {
            float bcol[4];
            #pragma unroll
            for (int ei = 0; ei < 4; ++ei)
                bcol[ei] = bias[h * 64 + ei * 16 + l16] * bsc;
            #pragma unroll
            for (int st = 0; st < 2; ++st) {
                const int srow = w * 32 + st * 16 + l16;
                bf16x8 a0 = *(const bf16x8*)&xs[srow][((lg    ) ^ (srow & 7)) * 8];
                bf16x8 a1 = *(const bf16x8*)&xs[srow][((4 + lg) ^ (srow & 7)) * 8];
                #pragma unroll
                for (int ei = 0; ei < 4; ++ei) {
                    const int erow = ei * 16 + l16;
                    bf16x8 b0 = *(const bf16x8*)&Wl[erow][((lg    ) ^ (erow & 7)) * 8];
                    bf16x8 b1 = *(const bf16x8*)&Wl[erow][((4 + lg) ^ (erow & 7)) * 8];
                    f32x4 acc = {0.f, 0.f, 0.f, 0.f};
                    acc = __builtin_amdgcn_mfma_f32_16x16x32_bf16(a0, b0, acc, 0, 0, 0);
                    acc = __builtin_amdgcn_mfma_f32_16x16x32_bf16(a1, b1, acc, 0, 0, 0);
                    #pragma unroll
                    for (int r = 0; r < 4; ++r)
                        ts[(w * 32 + st * 16 + 4 * lg + r) * 80 + ei * 16 + l16] =
                            (bf16)(acc[r] + bcol[ei]);
                }
            }
            __syncthreads();
            bf16* out = (p == 0) ? Qb : Kb;
            #pragma unroll
            for (int i = 0; i < 4; ++i) {
                int idx = tid + i * 256;
                int r = idx >> 3, g = idx & 7;
                uint4 v = *(const uint4*)&ts[r * 80 + g * 8];
                *(uint4*)(out + (bh * S + s0 + r) * 64 + g * 8) = v;
            }
        } else {
            float brow[4];
            #pragma unroll
            for (int r = 0; r < 4; ++r)
                brow[r] = bias[h * 64 + w * 16 + 4 * lg + r];
            const int erow = w * 16 + l16;
            bf16x8 a0 = *(const bf16x8*)&Wl[erow][((lg    ) ^ (erow & 7)) * 8];
            bf16x8 a1 = *(const bf16x8*)&Wl[erow][((4 + lg) ^ (erow & 7)) * 8];
            #pragma unroll
            for (int st = 0; st < 8; ++st) {
                const int srow = st * 16 + l16;
                bf16x8 b0 = *(const bf16x8*)&xs[srow][((lg    ) ^ (srow & 7)) * 8];
                bf16x8 b1 = *(const bf16x8*)&xs[srow][((4 + lg) ^ (srow & 7)) * 8];
                f32x4 acc = {0.f, 0.f, 0.f, 0.f};
                acc = __builtin_amdgcn_mfma_f32_16x16x32_bf16(a0, b0, acc, 0, 0, 0);
                acc = __builtin_amdgcn_mfma_f32_16x16x32_bf16(a1, b1, acc, 0, 0, 0);
                #pragma unroll
                for (int r = 0; r < 4; ++r)
                    ts[(w * 16 + 4 * lg + r) * 136 + st * 16 + l16] =
                        (bf16)(acc[r] + brow[r]);
            }
            __syncthreads();
            #pragma unroll
            for (int i = 0; i < 4; ++i) {
                int idx = tid + i * 256;
                int r = idx >> 4, g = idx & 15;
                uint4 v = *(const uint4*)&ts[r * 136 + g * 8];
                *(uint4*)(Vt + (bh * 64 + r) * S + s0 + g * 8) = v;
            }
        }
    }
}

// ---------------------------------------------------------------------------
// Kernel 3: causal flash attention — R20 base + T15 att[2] double-pipeline:
// per iteration, QK^T(t) overlaps softmax+PV(t-1) (MFMA pipe || VALU pipe).
// Unroll-2 (nt always even) with named pA/pB (rule #20: no runtime idx).
// V ds_write delayed one iter (held in regs) so no slot is written while
// other warps may still read it; K dbuf + V dbuf, barriers unchanged.
// ---------------------------------------------------------------------------
__global__ __launch_bounds__(512) void attn(
    const bf16* __restrict__ Qb, const bf16* __restrict__ Kb,
    const bf16* __restrict__ Vt, bf16* __restrict__ ctx)
{
    const int lin = blockIdx.y * 8 + blockIdx.x;   // 0..1023
    const int bh  = lin & 63;                      // b*H + h
    const int qt  = 15 - (lin >> 6);               // heavy tiles dispatch first
    const int b = bh >> 4, h = bh & 15;
    const int tid = threadIdx.x;
    const int w = tid >> 6;          // warp 0..7
    const int l = tid & 63;
    const int l16 = l & 15, lg = l >> 4;

    __shared__ __align__(16) bf16 Kl[2][64][64];
    __shared__ __align__(16) bf16 Vl[2][64][64];
    __shared__ __align__(16) bf16 Pl[8][16][72];

    const bf16* Qp = Qb + (size_t)bh * S * 64;
    const bf16* Kp = Kb + (size_t)bh * S * 64;
    const bf16* Vp = Vt + (size_t)bh * 64 * S;

    const int str = tid >> 3;
    const int stc = tid & 7;
    const int sws = (stc ^ (str & 7)) * 8;

    int foff0[4], foff1[4];
    #pragma unroll
    for (int s = 0; s < 4; ++s) {
        foff0[s] = (16 * s + l16) * 64 + ((lg    ) ^ (l16 & 7)) * 8;
        foff1[s] = (16 * s + l16) * 64 + ((4 + lg) ^ (l16 & 7)) * 8;
    }
    bf16* Plw = &Pl[w][0][0];
    const int pwr = l16 * 72 + 4 * lg;         // P write col base (s adds 16s)
    const int prd = l16 * 72 + 8 * lg;         // P read offset (second +32)

    const bf16 one_ = (bf16)1.0f;
    const bf16x8 ones = {one_, one_, one_, one_, one_, one_, one_, one_};

    const int qw0  = qt * 128 + w * 16;
    const int qabs = qw0 + l16;
    const int nt   = 2 * qt + 2;               // always even

    bf16x8 qf0 = *(const bf16x8*)(Qp + (size_t)qabs * 64 + lg * 8);
    bf16x8 qf1 = *(const bf16x8*)(Qp + (size_t)qabs * 64 + 32 + lg * 8);

    f32x4 o[4] = {};
    float m_run = -1e30f, l_run = 0.f;
    float pA[16], pB[16];

    {   // prologue: stage tile 0 (K and V) into slot 0
        uint4 kreg = *(const uint4*)(Kp + (size_t)str * 64 + stc * 8);
        uint4 vreg = *(const uint4*)(Vp + (size_t)str * S + stc * 8);
        *(uint4*)&Kl[0][str][sws] = kreg;
        *(uint4*)&Vl[0][str][sws] = vreg;
    }

#define QK_MASK(tt, kslot, P) do {                                           \
    const bf16* Kbase_ = &Kl[kslot][0][0];                                   \
    __builtin_amdgcn_s_setprio(1);                                           \
    _Pragma("unroll") for (int s_ = 0; s_ < 4; ++s_) {                       \
        f32x4 sc_ = {0.f, 0.f, 0.f, 0.f};                                    \
        bf16x8 ka_ = *(const bf16x8*)(Kbase_ + foff0[s_]);                   \
        bf16x8 kb_ = *(const bf16x8*)(Kbase_ + foff1[s_]);                   \
        sc_ = __builtin_amdgcn_mfma_f32_16x16x32_bf16(ka_, qf0, sc_, 0,0,0); \
        sc_ = __builtin_amdgcn_mfma_f32_16x16x32_bf16(kb_, qf1, sc_, 0,0,0); \
        P[4*s_+0]=sc_[0]; P[4*s_+1]=sc_[1]; P[4*s_+2]=sc_[2]; P[4*s_+3]=sc_[3]; } \
    __builtin_amdgcn_s_setprio(0);                                           \
    const int kv0_ = (tt) * 64;                                              \
    if (kv0_ + 63 > qw0) {                                                   \
        _Pragma("unroll") for (int i_ = 0; i_ < 16; ++i_) {                  \
            const int kvloc_ = 16 * (i_ >> 2) + 4 * lg + (i_ & 3);           \
            if (kv0_ + kvloc_ > qabs) P[i_] = -1e30f; } }                    \
} while (0)

#define SM_PV(vslot, P) do {                                                 \
    const bf16* Vbase_ = &Vl[vslot][0][0];                                   \
    const float a0_ = max3(P[0],  P[1],  P[2]);                              \
    const float a1_ = max3(P[3],  P[4],  P[5]);                              \
    const float a2_ = max3(P[6],  P[7],  P[8]);                              \
    const float a3_ = max3(P[9],  P[10], P[11]);                             \
    const float a4_ = max3(P[12], P[13], P[14]);                             \
    const float lmx_ = fmaxf(max3(a0_, a1_, a2_), max3(a3_, a4_, P[15]));    \
    if (!__all(lmx_ <= m_run + DTHR)) {                                      \
        float mx_ = fmaxf(lmx_, __shfl_xor(lmx_, 16));                       \
        mx_ = fmaxf(mx_, __shfl_xor(mx_, 32));                               \
        const float m_new_ = fmaxf(m_run, mx_);                              \
        const float corr_ = exp2_fast(m_run - m_new_);                       \
        l_run *= corr_;                                                      \
        _Pragma("unroll") for (int d_ = 0; d_ < 4; ++d_) {                   \
            o[d_][0] *= corr_; o[d_][1] *= corr_;                            \
            o[d_][2] *= corr_; o[d_][3] *= corr_; }                          \
        m_run = m_new_; }                                                    \
    _Pragma("unroll") for (int i_ = 0; i_ < 16; ++i_)                        \
        P[i_] = exp2_fast(P[i_] - m_run);                                    \
    _Pragma("unroll") for (int s_ = 0; s_ < 4; ++s_) {                       \
        u32x2 pw_;                                                           \
        pw_[0] = pk_bf16(P[4*s_+0], P[4*s_+1]);                              \
        pw_[1] = pk_bf16(P[4*s_+2], P[4*s_+3]);                              \
        *(u32x2*)(Plw + pwr + 16 * s_) = pw_; }                              \
    asm volatile("s_waitcnt lgkmcnt(0)" ::: "memory");                       \
    bf16x8 pf0_ = *(const bf16x8*)(Plw + prd);                               \
    bf16x8 pf1_ = *(const bf16x8*)(Plw + prd + 32);                          \
    __builtin_amdgcn_s_setprio(1);                                           \
    f32x4 o5_ = {0.f, 0.f, 0.f, 0.f};                                        \
    o5_ = __builtin_amdgcn_mfma_f32_16x16x32_bf16(ones, pf0_, o5_, 0,0,0);   \
    o5_ = __builtin_amdgcn_mfma_f32_16x16x32_bf16(ones, pf1_, o5_, 0,0,0);   \
    _Pragma("unroll") for (int d_ = 0; d_ < 4; ++d_) {                       \
        bf16x8 v0_ = *(const bf16x8*)(Vbase_ + foff0[d_]);                   \
        bf16x8 v1_ = *(const bf16x8*)(Vbase_ + foff1[d_]);                   \
        o[d_] = __builtin_amdgcn_mfma_f32_16x16x32_bf16(v0_, pf0_, o[d_], 0,0,0); \
        o[d_] = __builtin_amdgcn_mfma_f32_16x16x32_bf16(v1_, pf1_, o[d_], 0,0,0); } \
    __builtin_amdgcn_s_setprio(0);                                           \
    l_run += o5_[0];                                                         \
} while (0)

    uint4 vhA, vhB;                 // V regs held one iteration
    #pragma unroll 1
    for (int t = 0; t < nt; t += 2) {
        // ===== even sub-iter: tile t (QK), tile t-1 (SM+PV) =====
        __syncthreads();            // K(t)/V(t-1 slots) settled per schedule
        uint4 kregA;
        {   // load tile t+1 (always exists: t <= nt-2)
            const int kv1 = (t + 1) * 64;
            kregA = *(const uint4*)(Kp + (size_t)(kv1 + str) * 64 + stc * 8);
            vhA   = *(const uint4*)(Vp + (size_t)str * S + kv1 + stc * 8);
        }
        const bool doT = (t * 64 < qw0 + 16);
        if (doT) QK_MASK(t, 0, pA);
        if (t > 0 && (t - 1) * 64 < qw0 + 16) SM_PV(1, pB);
        *(uint4*)&Kl[1][str][sws] = kregA;            // K(t+1)
        if (t > 0) *(uint4*)&Vl[0][str][sws] = vhB;   // V(t), held from t-1

        // ===== odd sub-iter: tile t+1 (QK), tile t (SM+PV) =====
        __syncthreads();
        const bool more = (t + 2 < nt);
        uint4 kregB;
        if (more) {
            const int kv2 = (t + 2) * 64;
            kregB = *(const uint4*)(Kp + (size_t)(kv2 + str) * 64 + stc * 8);
            vhB   = *(const uint4*)(Vp + (size_t)str * S + kv2 + stc * 8);
        }
        if ((t + 1) * 64 < qw0 + 16) QK_MASK(t + 1, 1, pB);
        if (doT) SM_PV(0, pA);
        if (more) *(uint4*)&Kl[0][str][sws] = kregB;  // K(t+2)
        *(uint4*)&Vl[1][str][sws] = vhA;              // V(t+1)
    }
    __syncthreads();                // V(nt-1) visible to all warps
    if ((nt - 1) * 64 < qw0 + 16) SM_PV(1, pB);

#undef QK_MASK
#undef SM_PV

    const float il = 1.0f / l_run;
    bf16* crow = ctx + ((size_t)b * S + qabs) * E + h * 64;
    #pragma unroll
    for (int ds = 0; ds < 4; ++ds) {
        u32x2 pw;
        pw[0] = pk_bf16(o[ds][0] * il, o[ds][1] * il);
        pw[1] = pk_bf16(o[ds][2] * il, o[ds][3] * il);
        *(u32x2*)(crow + 16 * ds + 4 * lg) = pw;
    }
}

// ---------------------------------------------------------------------------
// Kernel 4: out = ctx[8192x1024] @ Wp[1024x1024] + bp, fp32 out.
// R18-exact (measured best ~12 us): 2-phase gl16 dbuf (64 KB LDS,
// 2 blocks/CU), XCD remap, direct scalar C-write.
// ---------------------------------------------------------------------------
__global__ __launch_bounds__(256) void out_gemm(
    const bf16* __restrict__ A, const bf16* __restrict__ Bt,
    const float* __restrict__ bp, float* __restrict__ C)
{
    const int lin = blockIdx.y * 8 + blockIdx.x;
    const int c   = lin & 7;
    const int k   = lin >> 3;
    const int n0  = (k & 7) * 128;
    const int m0  = (((k >> 3) << 3) | c) * 128;
    const int tid = threadIdx.x;
    const int w = tid >> 6, l = tid & 63;
    const int l16 = l & 15, lg = l >> 4;
    const int wm = w >> 1, wn = w & 1;

    __shared__ __align__(16) bf16 Al[2][128][64];   // 32 KB
    __shared__ __align__(16) bf16 Bl[2][128][64];   // 32 KB

    f32x4 acc[4][4] = {};

    const int r8 = l >> 3;
    const int chunk = ((l & 7) ^ r8) * 8;

    // prologue: DMA tile k0=0 into buffer 0
    #pragma unroll
    for (int i = 0; i < 4; ++i) {
        const int rb = 8 * w + 32 * i;
        gl16(A  + (size_t)(m0 + rb + r8) * E + chunk, &Al[0][rb][0]);
        gl16(Bt + (size_t)(n0 + rb + r8) * E + chunk, &Bl[0][rb][0]);
    }

    int cur = 0;
    for (int k0 = 0; k0 < E; k0 += 64) {
        __syncthreads();                    // buf[cur] DMA drained (vmcnt 0)
        if (k0 + 64 < E) {                  // DMA next tile into buf[cur^1]
            #pragma unroll
            for (int i = 0; i < 4; ++i) {
                const int rb = 8 * w + 32 * i;
                gl16(A  + (size_t)(m0 + rb + r8) * E + k0 + 64 + chunk,
                     &Al[cur ^ 1][rb][0]);
                gl16(Bt + (size_t)(n0 + rb + r8) * E + k0 + 64 + chunk,
                     &Bl[cur ^ 1][rb][0]);
            }
        }
        #pragma unroll
        for (int ks = 0; ks < 2; ++ks) {
            bf16x8 af[4], bfr[4];
            #pragma unroll
            for (int mi = 0; mi < 4; ++mi) {
                int r = wm * 64 + mi * 16 + l16;
                af[mi] = *(const bf16x8*)&Al[cur][r][((ks * 4 + lg) ^ (r & 7)) * 8];
            }
            #pragma unroll
            for (int ni = 0; ni < 4; ++ni) {
                int r = wn * 64 + ni * 16 + l16;
                bfr[ni] = *(const bf16x8*)&Bl[cur][r][((ks * 4 + lg) ^ (r & 7)) * 8];
            }
            #pragma unroll
            for (int mi = 0; mi < 4; ++mi)
                #pragma unroll
                for (int ni = 0; ni < 4; ++ni)
                    acc[mi][ni] = __builtin_amdgcn_mfma_f32_16x16x32_bf16(
                        af[mi], bfr[ni], acc[mi][ni], 0, 0, 0);
        }
        cur ^= 1;
    }

    #pragma unroll
    for (int ni = 0; ni < 4; ++ni) {
        const int col = n0 + wn * 64 + ni * 16 + l16;
        const float bias = bp[col];
        #pragma unroll
        for (int mi = 0; mi < 4; ++mi) {
            #pragma unroll
            for (int e = 0; e < 4; ++e) {
                int row = m0 + wm * 64 + mi * 16 + 4 * lg + e;
                C[(size_t)row * E + col] = acc[mi][ni][e] + bias;
            }
        }
    }
}

// ---------------------------------------------------------------------------
extern "C" void kernel_launch(void* const* d_in, const int* in_sizes, int n_in,
                              void* d_out, int out_size, void* d_ws, size_t ws_size,
                              hipStream_t stream)
{
    const float* xq = (const float*)d_in[0];
    const float* xk = (const float*)d_in[1];
    const float* xv = (const float*)d_in[2];
    const float* Wq = (const float*)d_in[3];
    const float* bq = (const float*)d_in[4];
    const float* Wk = (const float*)d_in[5];
    const float* bk = (const float*)d_in[6];
    const float* Wv = (const float*)d_in[7];
    const float* bv = (const float*)d_in[8];
    const float* Wp = (const float*)d_in[9];
    const float* bp = (const float*)d_in[10];
    float* out = (float*)d_out;

    char* ws = (char*)d_ws;
    const size_t sz_bhse = (size_t)B * H * S * HD;
    bf16* Qb  = (bf16*)ws;  ws += sz_bhse * 2;
    bf16* Kb  = (bf16*)ws;  ws += sz_bhse * 2;
    bf16* Vtw = (bf16*)ws;  ws += sz_bhse * 2;
    bf16* ctx = (bf16*)ws;  ws += (size_t)B * S * E * 2;
    bf16* Wpt = (bf16*)ws;  ws += (size_t)E * E * 2;
    bf16* Wt3 = (bf16*)ws;  ws += (size_t)3 * H * HD * HD * 2;

    prep_weights<<<dim3(16, 19), 256, 0, stream>>>(Wq, Wk, Wv, Wp, Wt3, Wpt);
    qkv_proj<<<dim3(S / 128, H, B), 256, 0, stream>>>(xq, xk, xv, Wt3,
                                                      bq, bk, bv, Qb, Kb, Vtw);
    attn<<<dim3(8, 128), 512, 0, stream>>>(Qb, Kb, Vtw, ctx);
    out_gemm<<<dim3(E / 128, (B * S) / 128), 256, 0, stream>>>(ctx, Wpt, bp, out);
}

// Round 22
// 125.922 us; speedup vs baseline: 1.0009x; 1.0009x over previous
//
#include <hip/hip_runtime.h>
#include <hip/hip_bf16.h>
#include <math.h>

typedef __bf16 bf16;
typedef __bf16 bf16x8 __attribute__((ext_vector_type(8)));
typedef float f32x4 __attribute__((ext_vector_type(4)));
typedef unsigned int u32x2 __attribute__((ext_vector_type(2)));

constexpr int B = 4, S = 2048, E = 1024, H = 16, HD = 64;

// 0.125 (1/sqrt(64)) * log2(e): scores in log2 domain -> raw v_exp_f32
constexpr float QSCALE = 0.125f * 1.44269504088896340736f;
// defer-max threshold (T13): 8 nats in log2 domain
constexpr float DTHR = 11.5f;

static __device__ __forceinline__ float exp2_fast(float x) {
#if __has_builtin(__builtin_amdgcn_exp2f)
    return __builtin_amdgcn_exp2f(x);
#else
    float r; asm("v_exp_f32 %0, %1" : "=v"(r) : "v"(x)); return r;
#endif
}

static __device__ __forceinline__ unsigned pk_bf16(float a, float b) {
    union { bf16 h[2]; unsigned u; } r;
    r.h[0] = (bf16)a; r.h[1] = (bf16)b;
    return r.u;
}

// 3-input max (clang fuses nested fmaxf to v_max3_f32 — T17)
static __device__ __forceinline__ float max3(float a, float b, float c) {
    return fmaxf(fmaxf(a, b), c);
}

// async global->LDS DMA, 16B/lane (block-wide staging only — measured win in
// out_gemm/qkv W-tile; measured regression in attn's wave-sliced staging).
static __device__ __forceinline__ void gl16(const void* g, void* l) {
    __builtin_amdgcn_global_load_lds(
        (__attribute__((address_space(1))) void*)g,
        (__attribute__((address_space(3))) void*)l,
        16, 0, 0);
}

// ---------------------------------------------------------------------------
// Kernel 0: fused weight prep.
// ---------------------------------------------------------------------------
__global__ __launch_bounds__(256) void prep_weights(
    const float* __restrict__ Wq, const float* __restrict__ Wk,
    const float* __restrict__ Wv, const float* __restrict__ Wp,
    bf16* __restrict__ Wt, bf16* __restrict__ Wpt)
{
    __shared__ float t[64][65];
    const int tid = threadIdx.x;
    const int x = blockIdx.x, y = blockIdx.y;
    if (y < 3) {
        const int h = x, p = y;
        const float* W = (p == 0) ? Wq : (p == 1) ? Wk : Wv;
        const float scale = (p == 0) ? QSCALE : 1.0f;
        #pragma unroll
        for (int i = 0; i < 16; ++i) {
            int idx = tid + i * 256;
            int d = idx >> 6, e = idx & 63;
            t[d][e] = W[(size_t)h * 4096 + d * 64 + e];
        }
        __syncthreads();
        bf16* dst = Wt + ((size_t)p * H + h) * 4096;
        #pragma unroll
        for (int i = 0; i < 16; ++i) {
            int idx = tid + i * 256;
            int e = idx >> 6, d = idx & 63;
            dst[e * 64 + d] = (bf16)(t[d][e] * scale);
        }
    } else {
        const int k0 = (y - 3) * 64, n0 = x * 64;
        #pragma unroll
        for (int i = 0; i < 16; ++i) {
            int idx = tid + i * 256;
            int r = idx >> 6, c = idx & 63;
            t[r][c] = Wp[(size_t)(k0 + r) * E + n0 + c];
        }
        __syncthreads();
        #pragma unroll
        for (int i = 0; i < 16; ++i) {
            int idx = tid + i * 256;
            int r = idx >> 6, c = idx & 63;
            Wpt[(size_t)(n0 + r) * E + k0 + c] = (bf16)t[c][r];
        }
    }
}

// ---------------------------------------------------------------------------
// Kernel 1: QKV projections via MFMA (verified 16x16x32 contract).
// W tile staged via gl16 (block-wide bf16, pre-swizzled src — measured R14).
// ---------------------------------------------------------------------------
__global__ __launch_bounds__(256) void qkv_proj(
    const float* __restrict__ xq, const float* __restrict__ xk, const float* __restrict__ xv,
    const bf16* __restrict__ Wt,
    const float* __restrict__ bq, const float* __restrict__ bk, const float* __restrict__ bv,
    bf16* __restrict__ Qb, bf16* __restrict__ Kb, bf16* __restrict__ Vt)
{
    const int b = blockIdx.z, h = blockIdx.y, s0 = blockIdx.x * 128;
    const int tid = threadIdx.x;
    const int w = tid >> 6, l = tid & 63;
    const int l16 = l & 15, lg = l >> 4;
    const size_t bh = (size_t)b * H + h;

    __shared__ __align__(16) bf16 xs[128][64];
    __shared__ __align__(16) bf16 Wl[64][64];
    __shared__ __align__(16) bf16 ts[10240];

    const int r8 = l >> 3;
    const int wchunk = ((l & 7) ^ r8) * 8;   // lane-constant swizzled chunk

    for (int p = 0; p < 3; ++p) {
        const float* x    = (p == 0) ? xq : (p == 1) ? xk : xv;
        const float* bias = (p == 0) ? bq : (p == 1) ? bk : bv;
        const float  bsc  = (p == 0) ? QSCALE : 1.0f;

        __syncthreads();
        // ---- W^T [64][64] bf16 via gl16 (2 issues/thread) ----
        const bf16* wsrc = Wt + ((size_t)p * H + h) * 4096;
        #pragma unroll
        for (int i = 0; i < 2; ++i) {
            const int rb = 8 * (w + 4 * i);
            gl16(wsrc + (size_t)(rb + r8) * 64 + wchunk, &Wl[rb][0]);
        }
        // ---- stage x tile [128][64] fp32 -> bf16 swizzled (reg path) ----
        #pragma unroll
        for (int i = 0; i < 4; ++i) {
            int idx = tid + i * 256;
            int r = idx >> 3, g = idx & 7;
            const float* src = &x[((size_t)b * S + s0 + r) * E + h * 64 + g * 8];
            float4 f0 = *(const float4*)src;
            float4 f1 = *(const float4*)(src + 4);
            union { bf16 h8[8]; uint4 u; } pk;
            pk.h8[0] = (bf16)f0.x; pk.h8[1] = (bf16)f0.y;
            pk.h8[2] = (bf16)f0.z; pk.h8[3] = (bf16)f0.w;
            pk.h8[4] = (bf16)f1.x; pk.h8[5] = (bf16)f1.y;
            pk.h8[6] = (bf16)f1.z; pk.h8[7] = (bf16)f1.w;
            *(uint4*)&xs[r][(g ^ (r & 7)) * 8] = pk.u;
        }
        __syncthreads();

        if (p < 2) {
            float bcol[4];
            #pragma unroll
            for (int ei = 0; ei < 4; ++ei)
                bcol[ei] = bias[h * 64 + ei * 16 + l16] * bsc;
            #pragma unroll
            for (int st = 0; st < 2; ++st) {
                const int srow = w * 32 + st * 16 + l16;
                bf16x8 a0 = *(const bf16x8*)&xs[srow][((lg    ) ^ (srow & 7)) * 8];
                bf16x8 a1 = *(const bf16x8*)&xs[srow][((4 + lg) ^ (srow & 7)) * 8];
                #pragma unroll
                for (int ei = 0; ei < 4; ++ei) {
                    const int erow = ei * 16 + l16;
                    bf16x8 b0 = *(const bf16x8*)&Wl[erow][((lg    ) ^ (erow & 7)) * 8];
                    bf16x8 b1 = *(const bf16x8*)&Wl[erow][((4 + lg) ^ (erow & 7)) * 8];
                    f32x4 acc = {0.f, 0.f, 0.f, 0.f};
                    acc = __builtin_amdgcn_mfma_f32_16x16x32_bf16(a0, b0, acc, 0, 0, 0);
                    acc = __builtin_amdgcn_mfma_f32_16x16x32_bf16(a1, b1, acc, 0, 0, 0);
                    #pragma unroll
                    for (int r = 0; r < 4; ++r)
                        ts[(w * 32 + st * 16 + 4 * lg + r) * 80 + ei * 16 + l16] =
                            (bf16)(acc[r] + bcol[ei]);
                }
            }
            __syncthreads();
            bf16* out = (p == 0) ? Qb : Kb;
            #pragma unroll
            for (int i = 0; i < 4; ++i) {
                int idx = tid + i * 256;
                int r = idx >> 3, g = idx & 7;
                uint4 v = *(const uint4*)&ts[r * 80 + g * 8];
                *(uint4*)(out + (bh * S + s0 + r) * 64 + g * 8) = v;
            }
        } else {
            float brow[4];
            #pragma unroll
            for (int r = 0; r < 4; ++r)
                brow[r] = bias[h * 64 + w * 16 + 4 * lg + r];
            const int erow = w * 16 + l16;
            bf16x8 a0 = *(const bf16x8*)&Wl[erow][((lg    ) ^ (erow & 7)) * 8];
            bf16x8 a1 = *(const bf16x8*)&Wl[erow][((4 + lg) ^ (erow & 7)) * 8];
            #pragma unroll
            for (int st = 0; st < 8; ++st) {
                const int srow = st * 16 + l16;
                bf16x8 b0 = *(const bf16x8*)&xs[srow][((lg    ) ^ (srow & 7)) * 8];
                bf16x8 b1 = *(const bf16x8*)&xs[srow][((4 + lg) ^ (srow & 7)) * 8];
                f32x4 acc = {0.f, 0.f, 0.f, 0.f};
                acc = __builtin_amdgcn_mfma_f32_16x16x32_bf16(a0, b0, acc, 0, 0, 0);
                acc = __builtin_amdgcn_mfma_f32_16x16x32_bf16(a1, b1, acc, 0, 0, 0);
                #pragma unroll
                for (int r = 0; r < 4; ++r)
                    ts[(w * 16 + 4 * lg + r) * 136 + st * 16 + l16] =
                        (bf16)(acc[r] + brow[r]);
            }
            __syncthreads();
            #pragma unroll
            for (int i = 0; i < 4; ++i) {
                int idx = tid + i * 256;
                int r = idx >> 4, g = idx & 15;
                uint4 v = *(const uint4*)&ts[r * 136 + g * 8];
                *(uint4*)(Vt + (bh * 64 + r) * S + s0 + g * 8) = v;
            }
        }
    }
}

// ---------------------------------------------------------------------------
// Kernel 3: causal flash attention — R20 base + T15 att[2] double-pipeline:
// per iteration, QK^T(t) overlaps softmax+PV(t-1) (MFMA pipe || VALU pipe).
// Unroll-2 (nt always even) with named pA/pB (rule #20: no runtime idx).
// V ds_write delayed one iter (held in regs) so no slot is written while
// other warps may still read it; K dbuf + V dbuf, barriers unchanged.
// ---------------------------------------------------------------------------
__global__ __launch_bounds__(512) void attn(
    const bf16* __restrict__ Qb, const bf16* __restrict__ Kb,
    const bf16* __restrict__ Vt, bf16* __restrict__ ctx)
{
    const int lin = blockIdx.y * 8 + blockIdx.x;   // 0..1023
    const int bh  = lin & 63;                      // b*H + h
    const int qt  = 15 - (lin >> 6);               // heavy tiles dispatch first
    const int b = bh >> 4, h = bh & 15;
    const int tid = threadIdx.x;
    const int w = tid >> 6;          // warp 0..7
    const int l = tid & 63;
    const int l16 = l & 15, lg = l >> 4;

    __shared__ __align__(16) bf16 Kl[2][64][64];
    __shared__ __align__(16) bf16 Vl[2][64][64];
    __shared__ __align__(16) bf16 Pl[8][16][72];

    const bf16* Qp = Qb + (size_t)bh * S * 64;
    const bf16* Kp = Kb + (size_t)bh * S * 64;
    const bf16* Vp = Vt + (size_t)bh * 64 * S;

    const int str = tid >> 3;
    const int stc = tid & 7;
    const int sws = (stc ^ (str & 7)) * 8;

    int foff0[4], foff1[4];
    #pragma unroll
    for (int s = 0; s < 4; ++s) {
        foff0[s] = (16 * s + l16) * 64 + ((lg    ) ^ (l16 & 7)) * 8;
        foff1[s] = (16 * s + l16) * 64 + ((4 + lg) ^ (l16 & 7)) * 8;
    }
    bf16* Plw = &Pl[w][0][0];
    const int pwr = l16 * 72 + 4 * lg;         // P write col base (s adds 16s)
    const int prd = l16 * 72 + 8 * lg;         // P read offset (second +32)

    const bf16 one_ = (bf16)1.0f;
    const bf16x8 ones = {one_, one_, one_, one_, one_, one_, one_, one_};

    const int qw0  = qt * 128 + w * 16;
    const int qabs = qw0 + l16;
    const int nt   = 2 * qt + 2;               // always even

    bf16x8 qf0 = *(const bf16x8*)(Qp + (size_t)qabs * 64 + lg * 8);
    bf16x8 qf1 = *(const bf16x8*)(Qp + (size_t)qabs * 64 + 32 + lg * 8);

    f32x4 o[4] = {};
    float m_run = -1e30f, l_run = 0.f;
    float pA[16], pB[16];

    {   // prologue: stage tile 0 (K and V) into slot 0
        uint4 kreg = *(const uint4*)(Kp + (size_t)str * 64 + stc * 8);
        uint4 vreg = *(const uint4*)(Vp + (size_t)str * S + stc * 8);
        *(uint4*)&Kl[0][str][sws] = kreg;
        *(uint4*)&Vl[0][str][sws] = vreg;
    }

#define QK_MASK(tt, kslot, P) do {                                           \
    const bf16* Kbase_ = &Kl[kslot][0][0];                                   \
    __builtin_amdgcn_s_setprio(1);                                           \
    _Pragma("unroll") for (int s_ = 0; s_ < 4; ++s_) {                       \
        f32x4 sc_ = {0.f, 0.f, 0.f, 0.f};                                    \
        bf16x8 ka_ = *(const bf16x8*)(Kbase_ + foff0[s_]);                   \
        bf16x8 kb_ = *(const bf16x8*)(Kbase_ + foff1[s_]);                   \
        sc_ = __builtin_amdgcn_mfma_f32_16x16x32_bf16(ka_, qf0, sc_, 0,0,0); \
        sc_ = __builtin_amdgcn_mfma_f32_16x16x32_bf16(kb_, qf1, sc_, 0,0,0); \
        P[4*s_+0]=sc_[0]; P[4*s_+1]=sc_[1]; P[4*s_+2]=sc_[2]; P[4*s_+3]=sc_[3]; } \
    __builtin_amdgcn_s_setprio(0);                                           \
    const int kv0_ = (tt) * 64;                                              \
    if (kv0_ + 63 > qw0) {                                                   \
        _Pragma("unroll") for (int i_ = 0; i_ < 16; ++i_) {                  \
            const int kvloc_ = 16 * (i_ >> 2) + 4 * lg + (i_ & 3);           \
            if (kv0_ + kvloc_ > qabs) P[i_] = -1e30f; } }                    \
} while (0)

#define SM_PV(vslot, P) do {                                                 \
    const bf16* Vbase_ = &Vl[vslot][0][0];                                   \
    const float a0_ = max3(P[0],  P[1],  P[2]);                              \
    const float a1_ = max3(P[3],  P[4],  P[5]);                              \
    const float a2_ = max3(P[6],  P[7],  P[8]);                              \
    const float a3_ = max3(P[9],  P[10], P[11]);                             \
    const float a4_ = max3(P[12], P[13], P[14]);                             \
    const float lmx_ = fmaxf(max3(a0_, a1_, a2_), max3(a3_, a4_, P[15]));    \
    if (!__all(lmx_ <= m_run + DTHR)) {                                      \
        float mx_ = fmaxf(lmx_, __shfl_xor(lmx_, 16));                       \
        mx_ = fmaxf(mx_, __shfl_xor(mx_, 32));                               \
        const float m_new_ = fmaxf(m_run, mx_);                              \
        const float corr_ = exp2_fast(m_run - m_new_);                       \
        l_run *= corr_;                                                      \
        _Pragma("unroll") for (int d_ = 0; d_ < 4; ++d_) {                   \
            o[d_][0] *= corr_; o[d_][1] *= corr_;                            \
            o[d_][2] *= corr_; o[d_][3] *= corr_; }                          \
        m_run = m_new_; }                                                    \
    _Pragma("unroll") for (int i_ = 0; i_ < 16; ++i_)                        \
        P[i_] = exp2_fast(P[i_] - m_run);                                    \
    _Pragma("unroll") for (int s_ = 0; s_ < 4; ++s_) {                       \
        u32x2 pw_;                                                           \
        pw_[0] = pk_bf16(P[4*s_+0], P[4*s_+1]);                              \
        pw_[1] = pk_bf16(P[4*s_+2], P[4*s_+3]);                              \
        *(u32x2*)(Plw + pwr + 16 * s_) = pw_; }                              \
    asm volatile("s_waitcnt lgkmcnt(0)" ::: "memory");                       \
    bf16x8 pf0_ = *(const bf16x8*)(Plw + prd);                               \
    bf16x8 pf1_ = *(const bf16x8*)(Plw + prd + 32);                          \
    __builtin_amdgcn_s_setprio(1);                                           \
    f32x4 o5_ = {0.f, 0.f, 0.f, 0.f};                                        \
    o5_ = __builtin_amdgcn_mfma_f32_16x16x32_bf16(ones, pf0_, o5_, 0,0,0);   \
    o5_ = __builtin_amdgcn_mfma_f32_16x16x32_bf16(ones, pf1_, o5_, 0,0,0);   \
    _Pragma("unroll") for (int d_ = 0; d_ < 4; ++d_) {                       \
        bf16x8 v0_ = *(const bf16x8*)(Vbase_ + foff0[d_]);                   \
        bf16x8 v1_ = *(const bf16x8*)(Vbase_ + foff1[d_]);                   \
        o[d_] = __builtin_amdgcn_mfma_f32_16x16x32_bf16(v0_, pf0_, o[d_], 0,0,0); \
        o[d_] = __builtin_amdgcn_mfma_f32_16x16x32_bf16(v1_, pf1_, o[d_], 0,0,0); } \
    __builtin_amdgcn_s_setprio(0);                                           \
    l_run += o5_[0];                                                         \
} while (0)

    uint4 vhA, vhB;                 // V regs held one iteration
    #pragma unroll 1
    for (int t = 0; t < nt; t += 2) {
        // ===== even sub-iter: tile t (QK), tile t-1 (SM+PV) =====
        __syncthreads();            // K(t)/V(t-1 slots) settled per schedule
        uint4 kregA;
        {   // load tile t+1 (always exists: t <= nt-2)
            const int kv1 = (t + 1) * 64;
            kregA = *(const uint4*)(Kp + (size_t)(kv1 + str) * 64 + stc * 8);
            vhA   = *(const uint4*)(Vp + (size_t)str * S + kv1 + stc * 8);
        }
        const bool doT = (t * 64 < qw0 + 16);
        if (doT) QK_MASK(t, 0, pA);
        if (t > 0 && (t - 1) * 64 < qw0 + 16) SM_PV(1, pB);
        *(uint4*)&Kl[1][str][sws] = kregA;            // K(t+1)
        if (t > 0) *(uint4*)&Vl[0][str][sws] = vhB;   // V(t), held from t-1

        // ===== odd sub-iter: tile t+1 (QK), tile t (SM+PV) =====
        __syncthreads();
        const bool more = (t + 2 < nt);
        uint4 kregB;
        if (more) {
            const int kv2 = (t + 2) * 64;
            kregB = *(const uint4*)(Kp + (size_t)(kv2 + str) * 64 + stc * 8);
            vhB   = *(const uint4*)(Vp + (size_t)str * S + kv2 + stc * 8);
        }
        if ((t + 1) * 64 < qw0 + 16) QK_MASK(t + 1, 1, pB);
        if (doT) SM_PV(0, pA);
        if (more) *(uint4*)&Kl[0][str][sws] = kregB;  // K(t+2)
        *(uint4*)&Vl[1][str][sws] = vhA;              // V(t+1)
    }
    __syncthreads();                // V(nt-1) visible to all warps
    if ((nt - 1) * 64 < qw0 + 16) SM_PV(1, pB);

#undef QK_MASK
#undef SM_PV

    const float il = 1.0f / l_run;
    bf16* crow = ctx + ((size_t)b * S + qabs) * E + h * 64;
    #pragma unroll
    for (int ds = 0; ds < 4; ++ds) {
        u32x2 pw;
        pw[0] = pk_bf16(o[ds][0] * il, o[ds][1] * il);
        pw[1] = pk_bf16(o[ds][2] * il, o[ds][3] * il);
        *(u32x2*)(crow + 16 * ds + 4 * lg) = pw;
    }
}

// ---------------------------------------------------------------------------
// Kernel 4: out = ctx[8192x1024] @ Wp[1024x1024] + bp, fp32 out.
// R18-exact (measured best ~12 us): 2-phase gl16 dbuf (64 KB LDS,
// 2 blocks/CU), XCD remap, direct scalar C-write.
// ---------------------------------------------------------------------------
__global__ __launch_bounds__(256) void out_gemm(
    const bf16* __restrict__ A, const bf16* __restrict__ Bt,
    const float* __restrict__ bp, float* __restrict__ C)
{
    const int lin = blockIdx.y * 8 + blockIdx.x;
    const int c   = lin & 7;
    const int k   = lin >> 3;
    const int n0  = (k & 7) * 128;
    const int m0  = (((k >> 3) << 3) | c) * 128;
    const int tid = threadIdx.x;
    const int w = tid >> 6, l = tid & 63;
    const int l16 = l & 15, lg = l >> 4;
    const int wm = w >> 1, wn = w & 1;

    __shared__ __align__(16) bf16 Al[2][128][64];   // 32 KB
    __shared__ __align__(16) bf16 Bl[2][128][64];   // 32 KB

    f32x4 acc[4][4] = {};

    const int r8 = l >> 3;
    const int chunk = ((l & 7) ^ r8) * 8;

    // prologue: DMA tile k0=0 into buffer 0
    #pragma unroll
    for (int i = 0; i < 4; ++i) {
        const int rb = 8 * w + 32 * i;
        gl16(A  + (size_t)(m0 + rb + r8) * E + chunk, &Al[0][rb][0]);
        gl16(Bt + (size_t)(n0 + rb + r8) * E + chunk, &Bl[0][rb][0]);
    }

    int cur = 0;
    for (int k0 = 0; k0 < E; k0 += 64) {
        __syncthreads();                    // buf[cur] DMA drained (vmcnt 0)
        if (k0 + 64 < E) {                  // DMA next tile into buf[cur^1]
            #pragma unroll
            for (int i = 0; i < 4; ++i) {
                const int rb = 8 * w + 32 * i;
                gl16(A  + (size_t)(m0 + rb + r8) * E + k0 + 64 + chunk,
                     &Al[cur ^ 1][rb][0]);
                gl16(Bt + (size_t)(n0 + rb + r8) * E + k0 + 64 + chunk,
                     &Bl[cur ^ 1][rb][0]);
            }
        }
        #pragma unroll
        for (int ks = 0; ks < 2; ++ks) {
            bf16x8 af[4], bfr[4];
            #pragma unroll
            for (int mi = 0; mi < 4; ++mi) {
                int r = wm * 64 + mi * 16 + l16;
                af[mi] = *(const bf16x8*)&Al[cur][r][((ks * 4 + lg) ^ (r & 7)) * 8];
            }
            #pragma unroll
            for (int ni = 0; ni < 4; ++ni) {
                int r = wn * 64 + ni * 16 + l16;
                bfr[ni] = *(const bf16x8*)&Bl[cur][r][((ks * 4 + lg) ^ (r & 7)) * 8];
            }
            #pragma unroll
            for (int mi = 0; mi < 4; ++mi)
                #pragma unroll
                for (int ni = 0; ni < 4; ++ni)
                    acc[mi][ni] = __builtin_amdgcn_mfma_f32_16x16x32_bf16(
                        af[mi], bfr[ni], acc[mi][ni], 0, 0, 0);
        }
        cur ^= 1;
    }

    #pragma unroll
    for (int ni = 0; ni < 4; ++ni) {
        const int col = n0 + wn * 64 + ni * 16 + l16;
        const float bias = bp[col];
        #pragma unroll
        for (int mi = 0; mi < 4; ++mi) {
            #pragma unroll
            for (int e = 0; e < 4; ++e) {
                int row = m0 + wm * 64 + mi * 16 + 4 * lg + e;
                C[(size_t)row * E + col] = acc[mi][ni][e] + bias;
            }
        }
    }
}

// ---------------------------------------------------------------------------
extern "C" void kernel_launch(void* const* d_in, const int* in_sizes, int n_in,
                              void* d_out, int out_size, void* d_ws, size_t ws_size,
                              hipStream_t stream)
{
    const float* xq = (const float*)d_in[0];
    const float* xk = (const float*)d_in[1];
    const float* xv = (const float*)d_in[2];
    const float* Wq = (const float*)d_in[3];
    const float* bq = (const float*)d_in[4];
    const float* Wk = (const float*)d_in[5];
    const float* bk = (const float*)d_in[6];
    const float* Wv = (const float*)d_in[7];
    const float* bv = (const float*)d_in[8];
    const float* Wp = (const float*)d_in[9];
    const float* bp = (const float*)d_in[10];
    float* out = (float*)d_out;

    char* ws = (char*)d_ws;
    const size_t sz_bhse = (size_t)B * H * S * HD;
    bf16* Qb  = (bf16*)ws;  ws += sz_bhse * 2;
    bf16* Kb  = (bf16*)ws;  ws += sz_bhse * 2;
    bf16* Vtw = (bf16*)ws;  ws += sz_bhse * 2;
    bf16* ctx = (bf16*)ws;  ws += (size_t)B * S * E * 2;
    bf16* Wpt = (bf16*)ws;  ws += (size_t)E * E * 2;
    bf16* Wt3 = (bf16*)ws;  ws += (size_t)3 * H * HD * HD * 2;

    prep_weights<<<dim3(16, 19), 256, 0, stream>>>(Wq, Wk, Wv, Wp, Wt3, Wpt);
    qkv_proj<<<dim3(S / 128, H, B), 256, 0, stream>>>(xq, xk, xv, Wt3,
                                                      bq, bk, bv, Qb, Kb, Vtw);
    attn<<<dim3(8, 128), 512, 0, stream>>>(Qb, Kb, Vtw, ctx);
    out_gemm<<<dim3(E / 128, (B * S) / 128), 256, 0, stream>>>(ctx, Wpt, bp, out);
}